// Round 2
// baseline (252.258 us; speedup 1.0000x reference)
//
#include <hip/hip_runtime.h>

// LabelLoss: out[b] = sum_{n,c<7} (pred[b,n,c] - gt[b,n,c])^2
// pred/gt: [256, 16384, 8] fp32.
//
// History:
//  R1-R4: ~100 us (2.7 TB/s) regular loads, structure-invariant -> cache-path
//         ceiling, not MLP/occupancy (in-flight bytes/CU ~256KB vs ~10KB
//         needed to cover HBM latency).
//  R6-R7: __builtin_nontemporal_load (nt = L1 bypass) + double-buffered
//         pipeline -> ~75 us (3.6 TB/s read).
//  R8:    inline-asm global_load sc0 sc1 nt with MANUAL vmcnt -> core dump.
//         Untracked VMEM in a compiler-scheduled loop is a register-lifetime
//         hazard (late writeback into a reallocated VGPR -> bad address).
//         DO NOT hand-roll untracked loads here.
//  R9 (this): same cache-policy experiment, compiler-tracked path:
//         make_buffer_rsrc + raw_buffer_load_b128 with aux CPol
//         sc0|nt|sc1 (1|2|16 = 19) -> buffer_load_dwordx4 ... sc0 sc1 nt
//         (system-scope streaming read, bypass L1 AND L2). The compiler
//         still owns vmcnt + register allocation, so no hazard surface.
//         __has_builtin-gated; falls back to the known-good nt-load kernel.

#define THREADS 256
#define SPLIT 8                               // blocks per batch row
#define F4_PER_BATCH (16384 * 2)              // 32768 float4s per batch per input
#define F4_PER_BLOCK (F4_PER_BATCH / SPLIT)   // 4096
#define DEPTH 4                               // float4s per thread per chunk
#define CHUNK (THREADS * DEPTH)               // 1024 float4s per chunk
#define NCHUNK (F4_PER_BLOCK / CHUNK)         // 4 chunks per block (even)

typedef float vfloat4 __attribute__((ext_vector_type(4)));
typedef unsigned int vuint4 __attribute__((ext_vector_type(4)));

#if defined(__has_builtin)
#  if __has_builtin(__builtin_amdgcn_make_buffer_rsrc) && \
      __has_builtin(__builtin_amdgcn_raw_buffer_load_b128)
#    define USE_BUFFER_STREAM 1
#  endif
#endif

#ifdef USE_BUFFER_STREAM
// System-scope streaming load through the buffer path. aux=19 sets
// CPol bits GLC(1)|SLC(2)|SCC(16) which gfx950 assembles as sc0 nt sc1:
// bypass L1 (TCP) and L2 (TCC) allocation, non-temporal at the MALL.
// Compiler-tracked: vmcnt and register lifetimes are handled for us.
__device__ __forceinline__ vfloat4 stream_load(__amdgpu_buffer_rsrc_t r, int byte_off) {
    vuint4 u = __builtin_amdgcn_raw_buffer_load_b128(r, byte_off, 0, 19);
    return __builtin_bit_cast(vfloat4, u);
}
#endif

__global__ __launch_bounds__(THREADS) void label_loss_kernel(
    const vfloat4* __restrict__ pred,
    const vfloat4* __restrict__ gt,
    float* __restrict__ out)
{
    const int b   = blockIdx.x / SPLIT;
    const int seg = blockIdx.x % SPLIT;
    // Per-buffer float4 index; max = 255*32768 + 7*4096 + 255 ~= 8.4M,
    // *16 bytes = 134 MB < 2^31, so 32-bit byte offsets are safe.
    const int base_f4 = b * F4_PER_BATCH + seg * F4_PER_BLOCK + (int)threadIdx.x;

    // Channel-7 mask: float4 index parity == tid&1 (all strides even):
    // lane-uniform, no divergence. Even float4 = ch0-3 (keep all, m=1),
    // odd float4 = ch4-7 (mask .w = ch7, m=0).
    const float m = (threadIdx.x & 1) ? 0.0f : 1.0f;

#ifdef USE_BUFFER_STREAM
    // Raw untyped SRD: stride=0, bounds check disabled, word3=0x00020000.
    __amdgpu_buffer_rsrc_t rp = __builtin_amdgcn_make_buffer_rsrc(
        (void*)pred, (short)0, 0xFFFFFFFFu, 0x00020000u);
    __amdgpu_buffer_rsrc_t rg = __builtin_amdgcn_make_buffer_rsrc(
        (void*)gt,   (short)0, 0xFFFFFFFFu, 0x00020000u);
#  define PLOAD(i4) stream_load(rp, (int)(i4) * 16)
#  define GLOAD(i4) stream_load(rg, (int)(i4) * 16)
#else
#  define PLOAD(i4) __builtin_nontemporal_load(&pred[i4])
#  define GLOAD(i4) __builtin_nontemporal_load(&gt[i4])
#endif

    vfloat4 Pa[DEPTH], Ga[DEPTH], Pb[DEPTH], Gb[DEPTH];
    float acc[DEPTH] = {0.0f, 0.0f, 0.0f, 0.0f};

#define LOAD(P_, G_, c) do {                                              \
    const int o_ = base_f4 + (c) * CHUNK;                                 \
    _Pragma("unroll")                                                     \
    for (int k = 0; k < DEPTH; ++k)                                       \
      P_[k] = PLOAD(o_ + k * THREADS);                                    \
    _Pragma("unroll")                                                     \
    for (int k = 0; k < DEPTH; ++k)                                       \
      G_[k] = GLOAD(o_ + k * THREADS);                                    \
  } while (0)

#define CONSUME(P_, G_) do {                                              \
    _Pragma("unroll")                                                     \
    for (int k = 0; k < DEPTH; ++k) {                                     \
      const vfloat4 d_ = P_[k] - G_[k];                                   \
      acc[k] += d_.x * d_.x + d_.y * d_.y + d_.z * d_.z + m * (d_.w * d_.w); \
    }                                                                     \
  } while (0)

    // Prologue: chunk 0 in flight (8 loads outstanding).
    LOAD(Pa, Ga, 0);

    // Steady state: always >= one chunk (8 loads) outstanding; the compiler
    // inserts counted vmcnt waits since these are tracked loads.
    #pragma unroll 1
    for (int c = 0; c + 2 < NCHUNK; c += 2) {
        LOAD(Pb, Gb, c + 1);
        CONSUME(Pa, Ga);
        LOAD(Pa, Ga, c + 2);
        CONSUME(Pb, Gb);
    }
    // Epilogue: Pa holds chunk NCHUNK-2 (NCHUNK is even).
    LOAD(Pb, Gb, NCHUNK - 1);
    CONSUME(Pa, Ga);
    CONSUME(Pb, Gb);

#undef LOAD
#undef CONSUME
#undef PLOAD
#undef GLOAD

    float v = (acc[0] + acc[1]) + (acc[2] + acc[3]);

    // 64-lane wave reduction
    #pragma unroll
    for (int off = 32; off > 0; off >>= 1)
        v += __shfl_down(v, off, 64);

    __shared__ float wsum[THREADS / 64];
    const int lane = threadIdx.x & 63;
    const int wave = threadIdx.x >> 6;
    if (lane == 0) wsum[wave] = v;
    __syncthreads();

    if (threadIdx.x == 0) {
        atomicAdd(&out[b], wsum[0] + wsum[1] + wsum[2] + wsum[3]);
    }
}

extern "C" void kernel_launch(void* const* d_in, const int* in_sizes, int n_in,
                              void* d_out, int out_size, void* d_ws, size_t ws_size,
                              hipStream_t stream) {
    const vfloat4* pred = (const vfloat4*)d_in[0];
    const vfloat4* gt   = (const vfloat4*)d_in[1];
    float* out = (float*)d_out;

    // d_out is re-poisoned to 0xAA before every launch; we accumulate with
    // atomics, so zero it first (async memset is graph-capture safe).
    (void)hipMemsetAsync(d_out, 0, (size_t)out_size * sizeof(float), stream);

    const int n_blocks = 256 * SPLIT;  // 2048 blocks, 8 per CU
    label_loss_kernel<<<dim3(n_blocks), dim3(THREADS), 0, stream>>>(pred, gt, out);
}

// Round 3
// 249.648 us; speedup vs baseline: 1.0105x; 1.0105x over previous
//
#include <hip/hip_runtime.h>

// LabelLoss: out[b] = sum_{n,c<7} (pred[b,n,c] - gt[b,n,c])^2
// pred/gt: [256, 16384, 8] fp32.
//
// History:
//  R1-R4: ~100 us (2.7 TB/s) regular loads, structure-invariant -> per-CU
//         read-service ceiling, not MLP/occupancy.
//  R6-R7: __builtin_nontemporal_load (nt = L1 bypass) + dbuf pipeline
//         -> ~75 us (3.6 TB/s read).
//  R8:    inline-asm global_load with MANUAL vmcnt -> core dump (untracked
//         VMEM = register-lifetime hazard; never hand-roll VGPR-dest loads).
//  R9:    buffer_load sc0 sc1 nt (L1+L2 bypass) -> NULL (252 vs 249 us).
//         L2 allocation policy is NOT the limiter.
//  R10 (this): model: per-CU miss-tracking cap in the TCP/TA vector-load
//         return path (cap*64B/latency ~= 14 GB/s/CU = 3.6 TB/s; explains
//         structure-invariance + policy sensitivity + 6.9 TB/s fills).
//         Try the ONE read path that skips VGPR-return miss machinery:
//         global_load_lds (LDS-DMA, the cp.async analog). Per-thread-
//         private LDS slots (each thread reads back only what its own
//         wave's DMA wrote) -> NO barriers, just counted vmcnt(2) with
//         double-buffered 16KB LDS. Compiler tracks the DMA in vmcnt, so
//         no R8-style hazard. aux=2 (nt) matches the 3.6 TB/s policy.

#define THREADS 256
#define SPLIT 8                               // blocks per batch row
#define F4_PER_BATCH (16384 * 2)              // 32768 float4s per batch per input
#define F4_PER_BLOCK (F4_PER_BATCH / SPLIT)   // 4096
#define NCHUNK (F4_PER_BLOCK / THREADS)       // 16 chunks per block

typedef float vfloat4 __attribute__((ext_vector_type(4)));

__global__ __launch_bounds__(THREADS) void label_loss_kernel(
    const vfloat4* __restrict__ pred,
    const vfloat4* __restrict__ gt,
    float* __restrict__ out)
{
    // [buffer][tensor][thread slot]; 2*2*256*16B = 16 KiB -> 8 blocks/CU.
    __shared__ vfloat4 lbuf[2][2][THREADS];

    const int tid  = (int)threadIdx.x;
    const int wave = tid >> 6;                 // LDS-DMA dest must be
                                               // wave-uniform base + lane*16
    const int b    = blockIdx.x / SPLIT;
    const int seg  = blockIdx.x % SPLIT;
    const int base_f4 = b * F4_PER_BATCH + seg * F4_PER_BLOCK + tid;

    // Channel-7 mask: float4 index parity == tid&1 (all strides even):
    // lane-uniform, no divergence.
    const float m = (tid & 1) ? 0.0f : 1.0f;

// Direct global->LDS DMA, 16B per lane. Dest ptr is wave-uniform; lane l
// lands at +l*16, i.e. slot (wave*64 + l) == tid. aux=2 = nt.
#define GLD_LDS(gp_, lp_)                                                   \
    __builtin_amdgcn_global_load_lds(                                       \
        (const __attribute__((address_space(1))) unsigned*)(gp_),           \
        (__attribute__((address_space(3))) unsigned*)(lp_), 16, 0, 2)

#define STAGE(s_, c_) do {                                                  \
    const int g_ = base_f4 + (c_) * THREADS;                                \
    GLD_LDS(&pred[g_], &lbuf[s_][0][wave << 6]);                            \
    GLD_LDS(&gt[g_],   &lbuf[s_][1][wave << 6]);                            \
  } while (0)

// Counted wait on the DMA queue (never 0 inside the loop). The consumer
// is a ds_read (a memory op), so the "memory" clobber orders it; the
// sched_barrier is cheap insurance against hoisting.
#define WAITN(n_) do {                                                      \
    asm volatile("s_waitcnt vmcnt(" #n_ ")" ::: "memory");                  \
    __builtin_amdgcn_sched_barrier(0);                                      \
  } while (0)

    float acc = 0.0f;

#define CONSUME(s_) do {                                                    \
    const vfloat4 P_ = lbuf[s_][0][tid];                                    \
    const vfloat4 G_ = lbuf[s_][1][tid];                                    \
    const vfloat4 d_ = P_ - G_;                                             \
    acc += d_.x * d_.x + d_.y * d_.y + d_.z * d_.z + m * (d_.w * d_.w);     \
  } while (0)

    // Prologue: chunk 0 in flight (2 DMA instrs outstanding).
    STAGE(0, 0);

    // Steady state: stage chunk c+1 into the other buffer (4 outstanding),
    // wait down to 2 (chunk c landed), consume chunk c. Buffer s is
    // re-staged two chunks after its ds_read -> no read/write race even
    // without barriers (slots are thread-private).
    #pragma unroll
    for (int c = 0; c < NCHUNK - 1; ++c) {
        STAGE((c + 1) & 1, c + 1);
        WAITN(2);
        CONSUME(c & 1);
    }
    // Epilogue: drain and consume the last chunk.
    WAITN(0);
    CONSUME((NCHUNK - 1) & 1);

#undef STAGE
#undef WAITN
#undef CONSUME
#undef GLD_LDS

    float v = acc;

    // 64-lane wave reduction
    #pragma unroll
    for (int off = 32; off > 0; off >>= 1)
        v += __shfl_down(v, off, 64);

    __shared__ float wsum[THREADS / 64];
    const int lane = tid & 63;
    if (lane == 0) wsum[wave] = v;
    __syncthreads();

    if (tid == 0) {
        atomicAdd(&out[b], wsum[0] + wsum[1] + wsum[2] + wsum[3]);
    }
}

extern "C" void kernel_launch(void* const* d_in, const int* in_sizes, int n_in,
                              void* d_out, int out_size, void* d_ws, size_t ws_size,
                              hipStream_t stream) {
    const vfloat4* pred = (const vfloat4*)d_in[0];
    const vfloat4* gt   = (const vfloat4*)d_in[1];
    float* out = (float*)d_out;

    // d_out is re-poisoned to 0xAA before every launch; we accumulate with
    // atomics, so zero it first (async memset is graph-capture safe).
    (void)hipMemsetAsync(d_out, 0, (size_t)out_size * sizeof(float), stream);

    const int n_blocks = 256 * SPLIT;  // 2048 blocks, 8 per CU
    label_loss_kernel<<<dim3(n_blocks), dim3(THREADS), 0, stream>>>(pred, gt, out);
}